// Round 4
// baseline (982.442 us; speedup 1.0000x reference)
//
#include <hip/hip_runtime.h>
#include <hip/hip_bf16.h>
#include <math.h>

#define B_SZ 1024
#define H_SZ 200
#define E_SZ 256
#define R_SZ 256
#define LN_EPS 1e-5f
#define NEG_HUGE -3.0e38f

typedef short bf16x8 __attribute__((ext_vector_type(8)));
typedef float f32x4 __attribute__((ext_vector_type(4)));

static __device__ inline short f2bf(float f) {
  union { float f; unsigned int u; } v; v.f = f;
  unsigned int u = v.u;
  unsigned int r = (u + 0x7fffu + ((u >> 16) & 1u)) >> 16;  // RNE
  return (short)(unsigned short)r;
}

// mask may arrive as 1-byte bool or promoted int32; flag picked at runtime.
static __device__ inline float mask_at(const void* m, size_t idx, int is_b8) {
  if (is_b8) return ((const unsigned char*)m)[idx] ? 1.f : 0.f;
  return ((const int*)m)[idx] ? 1.f : 0.f;
}

// ---- W (N x K row-major fp32) -> bf16 B-fragment swizzle ------------------
// Element (n,k) -> shorts[ ((n>>4)*(K/32) + (k>>5))*512
//                          + ((((k>>3)&3)<<4) | (n&15))*8 + (k&7) ]
// Same fragment semantics as the harness-verified agg Wsw staging.
static __device__ inline void wconv_item(const float* __restrict__ W,
                                         short* __restrict__ out, int N, int K,
                                         int idx) {
  const int k8pern = K >> 3;
  if (idx >= N * k8pern) return;
  const int n = idx / k8pern;
  const int k8 = idx - n * k8pern;
  const float4* s = (const float4*)(W + (size_t)n * K + k8 * 8);
  float4 a0 = s[0], a1 = s[1];
  bf16x8 v;
  v[0] = f2bf(a0.x); v[1] = f2bf(a0.y); v[2] = f2bf(a0.z); v[3] = f2bf(a0.w);
  v[4] = f2bf(a1.x); v[5] = f2bf(a1.y); v[6] = f2bf(a1.z); v[7] = f2bf(a1.w);
  const size_t off =
      (((size_t)(n >> 4) * (K >> 5) + (k8 >> 2)) * 64 +
       ((((k8 & 3)) << 4) | (n & 15))) << 3;
  *(bf16x8*)(out + off) = v;
}

// ---------------- K0: all weight conversions + mask-width detect -----------
// blocks 0..255: W1 (512x1024); 256..319: W2 (256x512); 320..383: Wc (512x256)
// 384..415: Wq (256x256); 416..447: Wrel (256x256); 448: detect.
__global__ __launch_bounds__(256) void wconv_all_kernel(
    const float* __restrict__ W1, const float* __restrict__ W2,
    const float* __restrict__ Wc, const float* __restrict__ Wq,
    const float* __restrict__ Wrel, const unsigned char* __restrict__ mask,
    short* __restrict__ w1b, short* __restrict__ w2b, short* __restrict__ wcb,
    short* __restrict__ wqb, short* __restrict__ wrelb,
    int* __restrict__ flag) {
  __shared__ int cnt;
  const int blk = blockIdx.x;
  const int t = threadIdx.x;
  if (blk < 256) {
    wconv_item(W1, w1b, 512, 1024, blk * 256 + t);
  } else if (blk < 320) {
    wconv_item(W2, w2b, 256, 512, (blk - 256) * 256 + t);
  } else if (blk < 384) {
    wconv_item(Wc, wcb, 512, 256, (blk - 320) * 256 + t);
  } else if (blk < 416) {
    wconv_item(Wq, wqb, 256, 256, (blk - 384) * 256 + t);
  } else if (blk < 448) {
    wconv_item(Wrel, wrelb, 256, 256, (blk - 416) * 256 + t);
  } else {
    // byte-mask (p=0.8): ~3277 nonzero bytes in first 4096; int32-mask: ~819.
    if (t == 0) cnt = 0;
    __syncthreads();
    int c = 0;
    for (int i = t; i < 4096; i += 256) c += mask[i] ? 1 : 0;
    atomicAdd(&cnt, c);
    __syncthreads();
    if (t == 0) *flag = (cnt > 2048) ? 1 : 0;
  }
}

// ---------------- K1: q_repr = e_emb @ W_q^T via MFMA (B x 256, K=256) -----
// 64 blocks x 16 rows; 4 waves; wave w covers cols [w*64, w*64+64).
__global__ __launch_bounds__(256) void qrepr_mfma_kernel(
    const float* __restrict__ e_emb, const short* __restrict__ Wqb,
    float* __restrict__ q_out) {
  const int t = threadIdx.x;
  const int lane = t & 63;
  const int w = t >> 6;
  const int r0 = blockIdx.x * 16;
  const int am = lane & 15;
  const int ak = (lane >> 4) * 8;
  f32x4 acc[4] = {};
  const short* wbase = Wqb + (size_t)(w * 4) * 8 * 512;
#pragma unroll
  for (int ks = 0; ks < 8; ++ks) {
    const float4* s4 =
        (const float4*)(e_emb + (size_t)(r0 + am) * E_SZ + ks * 32 + ak);
    float4 a0 = s4[0], a1 = s4[1];
    bf16x8 av;
    av[0] = f2bf(a0.x); av[1] = f2bf(a0.y); av[2] = f2bf(a0.z); av[3] = f2bf(a0.w);
    av[4] = f2bf(a1.x); av[5] = f2bf(a1.y); av[6] = f2bf(a1.z); av[7] = f2bf(a1.w);
#pragma unroll
    for (int s = 0; s < 4; ++s) {
      bf16x8 bv = *(const bf16x8*)(wbase + (((size_t)(s * 8 + ks)) * 64 + lane) * 8);
      acc[s] = __builtin_amdgcn_mfma_f32_16x16x32_bf16(av, bv, acc[s], 0, 0, 0);
    }
  }
#pragma unroll
  for (int s = 0; s < 4; ++s) {
    const int col = w * 64 + s * 16 + am;
#pragma unroll
    for (int reg = 0; reg < 4; ++reg) {
      const int row = (lane >> 4) * 4 + reg;  // C layout: row=(lane>>4)*4+reg
      q_out[(size_t)(r0 + row) * E_SZ + col] = acc[s][reg];
    }
  }
}

// ---------------- K2: fused messages GEMM + decay + online softmax + PNA ----
// v2: one block per batch row (grid 1024); W_rel B-fragments read from
// pre-swizzled GLOBAL buffer (L2-resident) instead of a 128 KB LDS copy.
// LDS drops 152.5 KB -> ~21.5 KB => 3 blocks/CU (was 1) for barrier overlap.
__global__ __launch_bounds__(512, 6) void agg_kernel(
    const float* __restrict__ rel, const float* __restrict__ ent,
    const int* __restrict__ htime, const int* __restrict__ qtime,
    const void* __restrict__ mask, const int* __restrict__ mflag,
    const short* __restrict__ wrelb, const float* __restrict__ qws,
    const float* __restrict__ e_emb, const float* __restrict__ log_gamma,
    short* __restrict__ comb) {
  __shared__ short Asw[8192];        // 16 KB: 32 rows x 256 r, A-frag order
  __shared__ float q_s[256];
  __shared__ float attn_acc[256];
  __shared__ float mean_b[256];
  __shared__ float max_b[256];
  __shared__ float s_part[128];
  __shared__ float decay_s[32];
  __shared__ float maskf_s[32];
  __shared__ float p_s[32];
  __shared__ float scal[4];          // {m, l, alpha, nv}

  const int t = threadIdx.x;
  const int lane = t & 63;
  const int w = t >> 6;
  const int rh = w >> 2;
  const int cg = w & 3;
  const int q4 = lane >> 4;
  const int cl = lane & 15;
  const float gamma = expf(log_gamma[0]);
  const int is_b8 = *mflag;
  const int b = blockIdx.x;

  if (t < 256) { attn_acc[t] = 0.f; q_s[t] = qws[(size_t)b * E_SZ + t]; }
  if (t == 0) { scal[0] = NEG_HUGE; scal[1] = 0.f; scal[2] = 0.f; scal[3] = 0.f; }
  float mean4[4] = {0.f, 0.f, 0.f, 0.f};
  float max4[4] = {NEG_HUGE, NEG_HUGE, NEG_HUGE, NEG_HUGE};
  const float qtf = (float)qtime[b];
  // wave's B-fragment base: csub = cg*4+sub, frag = ((csub*8+ks)*64+lane)*8
  const short* wwave = wrelb + ((size_t)cg * 4 * 8 * 64) * 8;
  __syncthreads();

  for (int tile = 0; tile < 7; ++tile) {
    const int h0 = tile * 32;
    // ---- stage A tile (32 rows x 256 r) into A-fragment order ----
    {
      const int row = t >> 4;         // 0..31
      const int rcc = t & 15;         // 16-wide r-chunk
      const int h = h0 + row;
      bf16x8 v0 = {}; bf16x8 v1 = {};
      if (h < H_SZ) {
        const float4* src =
            (const float4*)(rel + ((size_t)b * H_SZ + h) * R_SZ + rcc * 16);
        float4 a0 = src[0], a1 = src[1], a2 = src[2], a3 = src[3];
        v0[0] = f2bf(a0.x); v0[1] = f2bf(a0.y); v0[2] = f2bf(a0.z); v0[3] = f2bf(a0.w);
        v0[4] = f2bf(a1.x); v0[5] = f2bf(a1.y); v0[6] = f2bf(a1.z); v0[7] = f2bf(a1.w);
        v1[0] = f2bf(a2.x); v1[1] = f2bf(a2.y); v1[2] = f2bf(a2.z); v1[3] = f2bf(a2.w);
        v1[4] = f2bf(a3.x); v1[5] = f2bf(a3.y); v1[6] = f2bf(a3.z); v1[7] = f2bf(a3.w);
      }
      const int rh2 = row >> 4, rlow = row & 15;
      const int rr0 = rcc * 2, rr1 = rcc * 2 + 1;
      *(bf16x8*)(Asw + (((rh2 * 8 + (rr0 >> 2)) * 64 + (((rr0 & 3) << 4) | rlow)) << 3)) = v0;
      *(bf16x8*)(Asw + (((rh2 * 8 + (rr1 >> 2)) * 64 + (((rr1 & 3) << 4) | rlow)) << 3)) = v1;
    }
    if (t < 32) {
      const int h = h0 + t;
      float mf = 0.f, dc = 0.f;
      if (h < H_SZ) {
        mf = mask_at(mask, (size_t)b * H_SZ + h, is_b8);
        float td = fmaxf(qtf - (float)htime[(size_t)b * H_SZ + h], 0.f);
        dc = expf(-gamma * td);
      }
      maskf_s[t] = mf; decay_s[t] = dc;
    }
    __syncthreads();

    // ---- MFMA: rp[32x256] = relTile(32x256) x Wrel^T(256x256) ----
    f32x4 acc[4] = {};
    for (int ks = 0; ks < 8; ++ks) {
      bf16x8 av = *(bf16x8*)(Asw + (((rh * 8 + ks) * 64 + lane) << 3));
#pragma unroll
      for (int sub = 0; sub < 4; ++sub) {
        bf16x8 bv = *(const bf16x8*)(wwave + (((size_t)(sub * 8 + ks)) * 64 + lane) * 8);
        acc[sub] = __builtin_amdgcn_mfma_f32_16x16x32_bf16(av, bv, acc[sub], 0, 0, 0);
      }
    }

    // ---- epilogue: msg = rp*ent; mean/max partials; score partials ----
    float msgv[16];  // [reg][sub]
    float sc[4];
#pragma unroll
    for (int reg = 0; reg < 4; ++reg) {
      const int row = rh * 16 + q4 * 4 + reg;  // C layout: row=(lane>>4)*4+reg
      const int h = h0 + row;
      const float mf = maskf_s[row];
      const bool realrow = (h < H_SZ);
      float srow = 0.f;
#pragma unroll
      for (int sub = 0; sub < 4; ++sub) {
        const int e = cg * 64 + sub * 16 + cl;  // C layout: col=lane&15
        float entv = realrow ? ent[((size_t)b * H_SZ + h) * E_SZ + e] : 0.f;
        float m = acc[sub][reg] * entv;
        msgv[reg * 4 + sub] = m;
        mean4[sub] += mf * m;
        float cand = realrow ? (mf != 0.f ? m : 0.f) : NEG_HUGE;
        max4[sub] = fmaxf(max4[sub], cand);
        srow += q_s[e] * m;
      }
      sc[reg] = srow;
    }
#pragma unroll
    for (int m = 1; m <= 8; m <<= 1)
#pragma unroll
      for (int reg = 0; reg < 4; ++reg) sc[reg] += __shfl_xor(sc[reg], m, 64);
    if (cl == 0)
#pragma unroll
      for (int reg = 0; reg < 4; ++reg)
        s_part[(rh * 16 + q4 * 4 + reg) * 4 + cg] = sc[reg];
    __syncthreads();

    // ---- online softmax update (wave 0; rows duplicated in lane halves) --
    if (w == 0) {
      const int row = lane & 31;
      const int h = h0 + row;
      float srow = s_part[row * 4] + s_part[row * 4 + 1] +
                   s_part[row * 4 + 2] + s_part[row * 4 + 3];
      float s;
      if (h >= H_SZ) s = NEG_HUGE;
      else if (maskf_s[row] == 0.f) s = -1e9f;
      else s = decay_s[row] * srow * 0.0625f;  // / sqrt(256)
      float mt = s;
#pragma unroll
      for (int m = 1; m <= 16; m <<= 1) mt = fmaxf(mt, __shfl_xor(mt, m, 64));
      const float m_old = scal[0];
      const float m_new = fmaxf(m_old, mt);
      const float alpha = expf(m_old - m_new);
      const float p = expf(s - m_new);
      float lt = p;
#pragma unroll
      for (int m = 1; m <= 16; m <<= 1) lt += __shfl_xor(lt, m, 64);
      if (lane == 0) {
        scal[0] = m_new;
        scal[1] = scal[1] * alpha + lt;
        scal[2] = alpha;
      }
      if (lane < 32) p_s[row] = p;
    }
    __syncthreads();
    {
      const float alpha = scal[2];
      if (t < 256) attn_acc[t] *= alpha;
    }
    __syncthreads();
    // ---- attn accumulation: attn_acc[e] += sum_rows p[row]*msg ----
    float av4[4];
#pragma unroll
    for (int sub = 0; sub < 4; ++sub) {
      float v = 0.f;
#pragma unroll
      for (int reg = 0; reg < 4; ++reg)
        v += p_s[rh * 16 + q4 * 4 + reg] * msgv[reg * 4 + sub];
      v += __shfl_xor(v, 16, 64);
      v += __shfl_xor(v, 32, 64);
      av4[sub] = v;
    }
    if (q4 == 0)
#pragma unroll
      for (int sub = 0; sub < 4; ++sub)
        atomicAdd(&attn_acc[cg * 64 + sub * 16 + cl], av4[sub]);
    __syncthreads();
  }  // tiles

  // ---- finale: reduce mean/max, n_valid, write combined (bf16) ----
#pragma unroll
  for (int sub = 0; sub < 4; ++sub) {
    float mv = mean4[sub];
    mv += __shfl_xor(mv, 16, 64); mv += __shfl_xor(mv, 32, 64);
    float xv = max4[sub];
    xv = fmaxf(xv, __shfl_xor(xv, 16, 64));
    xv = fmaxf(xv, __shfl_xor(xv, 32, 64));
    mean4[sub] = mv; max4[sub] = xv;
  }
  if (rh == 0 && q4 == 0) {
#pragma unroll
    for (int sub = 0; sub < 4; ++sub) {
      mean_b[cg * 64 + sub * 16 + cl] = mean4[sub];
      max_b[cg * 64 + sub * 16 + cl] = max4[sub];
    }
  }
  if (t < H_SZ) atomicAdd(&scal[3], mask_at(mask, (size_t)b * H_SZ + t, is_b8));
  __syncthreads();
  if (rh == 1 && q4 == 0) {
#pragma unroll
    for (int sub = 0; sub < 4; ++sub) {
      const int e = cg * 64 + sub * 16 + cl;
      mean_b[e] += mean4[sub];
      max_b[e] = fmaxf(max_b[e], max4[sub]);
    }
  }
  __syncthreads();
  if (t < 256) {
    const float nv = fmaxf(scal[3], 1.f);
    const float l = scal[1];
    short* dst = comb + (size_t)b * 1024;
    dst[t] = f2bf(mean_b[t] / nv);
    dst[256 + t] = f2bf(max_b[t]);
    dst[512 + t] = f2bf(attn_acc[t] / l);
    dst[768 + t] = f2bf(e_emb[(size_t)b * E_SZ + t]);
  }
}

// ---------------- K3: MFMA GEMM + bias + LayerNorm (+ exact GELU) ----------
// Y[M=1024][N] = LN(X[M][K] @ W^T + bias) (optionally GELU).
// Grid: M/16 blocks, 256 threads = 4 waves; wave w owns cols [w*N/4,(w+1)*N/4).
template <int K, int N, bool GELU, bool IN_BF16, bool OUT_BF16>
__global__ __launch_bounds__(256) void mfma_mlp_kernel(
    const void* __restrict__ Xv, const short* __restrict__ Wswz,
    const float* __restrict__ bias, const float* __restrict__ lng,
    const float* __restrict__ lnb, void* __restrict__ Yv) {
  constexpr int NS = N / 64;   // 16-col subs per wave
  constexpr int KS = K / 32;   // K steps
  __shared__ float pre[16][N + 4];
  __shared__ float red[16][2];
  const int t = threadIdx.x;
  const int lane = t & 63;
  const int w = t >> 6;
  const int r0 = blockIdx.x * 16;
  const int am = lane & 15;          // A row / C col within sub
  const int ak = (lane >> 4) * 8;    // A k-offset within 32-chunk

  f32x4 acc[NS] = {};
  const short* wbase = Wswz + (size_t)(w * NS) * KS * 512;
#pragma unroll 2
  for (int ks = 0; ks < KS; ++ks) {
    bf16x8 av;
    if (IN_BF16) {
      const short* X = (const short*)Xv;
      av = *(const bf16x8*)(X + (size_t)(r0 + am) * K + ks * 32 + ak);
    } else {
      const float* X = (const float*)Xv;
      const float4* s = (const float4*)(X + (size_t)(r0 + am) * K + ks * 32 + ak);
      float4 a0 = s[0], a1 = s[1];
      av[0] = f2bf(a0.x); av[1] = f2bf(a0.y); av[2] = f2bf(a0.z); av[3] = f2bf(a0.w);
      av[4] = f2bf(a1.x); av[5] = f2bf(a1.y); av[6] = f2bf(a1.z); av[7] = f2bf(a1.w);
    }
#pragma unroll
    for (int s = 0; s < NS; ++s) {
      bf16x8 bv = *(const bf16x8*)(wbase + (((size_t)(s * KS + ks)) * 64 + lane) * 8);
      acc[s] = __builtin_amdgcn_mfma_f32_16x16x32_bf16(av, bv, acc[s], 0, 0, 0);
    }
  }
  // ---- bias + stash pre-activations in LDS ----
#pragma unroll
  for (int s = 0; s < NS; ++s) {
    const int col = w * (N / 4) + s * 16 + am;
    const float bv = bias[col];
#pragma unroll
    for (int reg = 0; reg < 4; ++reg) {
      const int row = (lane >> 4) * 4 + reg;  // C layout: row=(lane>>4)*4+reg
      pre[row][col] = acc[s][reg] + bv;
    }
  }
  __syncthreads();
  // ---- rowwise mean / var (16 rows x 16 chunks, strided = conflict-free) --
  {
    const int row = t >> 4, ch = t & 15;
    float s1 = 0.f, s2 = 0.f;
    for (int c = ch; c < N; c += 16) {
      float v = pre[row][c]; s1 += v; s2 += v * v;
    }
#pragma unroll
    for (int m = 1; m <= 8; m <<= 1) {
      s1 += __shfl_xor(s1, m, 64);
      s2 += __shfl_xor(s2, m, 64);
    }
    if (ch == 0) { red[row][0] = s1 / N; red[row][1] = s2 / N; }
  }
  __syncthreads();
  // ---- normalize (+GELU) and store, coalesced ----
  for (int i = t; i < 16 * N; i += 256) {
    const int row = i / N, c = i - row * N;
    const float mu = red[row][0];
    const float var = fmaxf(red[row][1] - mu * mu, 0.f);
    float x = (pre[row][c] - mu) * rsqrtf(var + LN_EPS) * lng[c] + lnb[c];
    if (GELU) x = 0.5f * x * (1.f + erff(x * 0.70710678118654752f));
    if (OUT_BF16) ((short*)Yv)[(size_t)(r0 + row) * N + c] = f2bf(x);
    else ((float*)Yv)[(size_t)(r0 + row) * N + c] = x;
  }
}

extern "C" void kernel_launch(void* const* d_in, const int* in_sizes, int n_in,
                              void* d_out, int out_size, void* d_ws,
                              size_t ws_size, hipStream_t stream) {
  const float* e_emb = (const float*)d_in[0];
  const float* ent = (const float*)d_in[1];
  const float* rel = (const float*)d_in[2];
  const int* ht = (const int*)d_in[3];
  const int* qt = (const int*)d_in[4];
  const void* mask = d_in[5];
  const float* Wrel = (const float*)d_in[6];
  const float* Wq = (const float*)d_in[7];
  const float* lg = (const float*)d_in[8];
  const float* W1 = (const float*)d_in[9];
  const float* b1 = (const float*)d_in[10];
  const float* ln1g = (const float*)d_in[11];
  const float* ln1b = (const float*)d_in[12];
  const float* W2 = (const float*)d_in[13];
  const float* b2 = (const float*)d_in[14];
  const float* ln2g = (const float*)d_in[15];
  const float* ln2b = (const float*)d_in[16];
  const float* Wc = (const float*)d_in[17];
  const float* bc = (const float*)d_in[18];
  const float* lncg = (const float*)d_in[19];
  const float* lncb = (const float*)d_in[20];

  // Workspace layout (peak 4.76 MB — within the envelope that passed):
  //   [0, 4K)                    mflag
  //   [4K, +1M)                  W1 bf16 swz
  //   [.., +256K)                W2 bf16 swz
  //   [.., +256K)                Wc bf16 swz
  //   [.., +128K)                Wq bf16 swz
  //   [.., +128K)                Wrel bf16 swz
  //   [.., +1M)                  q_ws fp32 (qrepr->agg), dead after agg;
  //                              t1 bf16 (mlp1->mlp2) overlaps the same slot
  //   [.., +2M)                  comb bf16 [1024][1024] (agg->mlp1)
  char* wsb = (char*)d_ws;
  int* mflag = (int*)wsb;
  short* w1b = (short*)(wsb + 4096);
  short* w2b = (short*)(wsb + 4096 + (1024u << 10));
  short* wcb = (short*)(wsb + 4096 + (1280u << 10));
  short* wqb = (short*)(wsb + 4096 + (1536u << 10));
  short* wrelb = (short*)(wsb + 4096 + (1664u << 10));
  float* q_ws = (float*)(wsb + 4096 + (1792u << 10));
  short* t1b = (short*)(wsb + 4096 + (1792u << 10));
  short* combb = (short*)(wsb + 4096 + (2816u << 10));
  float* dyn = (float*)d_out;                          // B x 256
  float* ctx = (float*)d_out + (size_t)B_SZ * E_SZ;    // B x 512

  (void)ws_size;

  wconv_all_kernel<<<449, 256, 0, stream>>>(
      W1, W2, Wc, Wq, Wrel, (const unsigned char*)mask,
      w1b, w2b, wcb, wqb, wrelb, mflag);
  qrepr_mfma_kernel<<<64, 256, 0, stream>>>(e_emb, wqb, q_ws);
  agg_kernel<<<1024, 512, 0, stream>>>(rel, ent, ht, qt, mask, mflag,
                                       wrelb, q_ws, e_emb, lg, combb);
  mfma_mlp_kernel<1024, 512, true, true, true>
      <<<64, 256, 0, stream>>>(combb, w1b, b1, ln1g, ln1b, t1b);
  mfma_mlp_kernel<512, 256, false, true, false>
      <<<64, 256, 0, stream>>>(t1b, w2b, b2, ln2g, ln2b, dyn);
  mfma_mlp_kernel<256, 512, true, false, false>
      <<<64, 256, 0, stream>>>(dyn, wcb, bc, lncg, lncb, ctx);
}

// Round 5
// 546.570 us; speedup vs baseline: 1.7975x; 1.7975x over previous
//
#include <hip/hip_runtime.h>
#include <hip/hip_bf16.h>
#include <math.h>

#define B_SZ 1024
#define H_SZ 200
#define E_SZ 256
#define R_SZ 256
#define LN_EPS 1e-5f
#define NEG_HUGE -3.0e38f

typedef short bf16x8 __attribute__((ext_vector_type(8)));
typedef float f32x4 __attribute__((ext_vector_type(4)));

static __device__ inline short f2bf(float f) {
  union { float f; unsigned int u; } v; v.f = f;
  unsigned int u = v.u;
  unsigned int r = (u + 0x7fffu + ((u >> 16) & 1u)) >> 16;  // RNE
  return (short)(unsigned short)r;
}

// mask may arrive as 1-byte bool or promoted int32; flag picked at runtime.
static __device__ inline float mask_at(const void* m, size_t idx, int is_b8) {
  if (is_b8) return ((const unsigned char*)m)[idx] ? 1.f : 0.f;
  return ((const int*)m)[idx] ? 1.f : 0.f;
}

// ---- W (N x K row-major fp32) -> bf16 B-fragment swizzle ------------------
// Element (n,k) -> shorts[ ((n>>4)*(K/32) + (k>>5))*512
//                          + ((((k>>3)&3)<<4) | (n&15))*8 + (k&7) ]
static __device__ inline void wconv_item(const float* __restrict__ W,
                                         short* __restrict__ out, int N, int K,
                                         int idx) {
  const int k8pern = K >> 3;
  if (idx >= N * k8pern) return;
  const int n = idx / k8pern;
  const int k8 = idx - n * k8pern;
  const float4* s = (const float4*)(W + (size_t)n * K + k8 * 8);
  float4 a0 = s[0], a1 = s[1];
  bf16x8 v;
  v[0] = f2bf(a0.x); v[1] = f2bf(a0.y); v[2] = f2bf(a0.z); v[3] = f2bf(a0.w);
  v[4] = f2bf(a1.x); v[5] = f2bf(a1.y); v[6] = f2bf(a1.z); v[7] = f2bf(a1.w);
  const size_t off =
      (((size_t)(n >> 4) * (K >> 5) + (k8 >> 2)) * 64 +
       ((((k8 & 3)) << 4) | (n & 15))) << 3;
  *(bf16x8*)(out + off) = v;
}

// ---------------- K0: all weight conversions + mask-width detect -----------
__global__ __launch_bounds__(256) void wconv_all_kernel(
    const float* __restrict__ W1, const float* __restrict__ W2,
    const float* __restrict__ Wc, const float* __restrict__ Wq,
    const float* __restrict__ Wrel, const unsigned char* __restrict__ mask,
    short* __restrict__ w1b, short* __restrict__ w2b, short* __restrict__ wcb,
    short* __restrict__ wqb, short* __restrict__ wrelb,
    int* __restrict__ flag) {
  __shared__ int cnt;
  const int blk = blockIdx.x;
  const int t = threadIdx.x;
  if (blk < 256) {
    wconv_item(W1, w1b, 512, 1024, blk * 256 + t);
  } else if (blk < 320) {
    wconv_item(W2, w2b, 256, 512, (blk - 256) * 256 + t);
  } else if (blk < 384) {
    wconv_item(Wc, wcb, 512, 256, (blk - 320) * 256 + t);
  } else if (blk < 416) {
    wconv_item(Wq, wqb, 256, 256, (blk - 384) * 256 + t);
  } else if (blk < 448) {
    wconv_item(Wrel, wrelb, 256, 256, (blk - 416) * 256 + t);
  } else {
    if (t == 0) cnt = 0;
    __syncthreads();
    int c = 0;
    for (int i = t; i < 4096; i += 256) c += mask[i] ? 1 : 0;
    atomicAdd(&cnt, c);
    __syncthreads();
    if (t == 0) *flag = (cnt > 2048) ? 1 : 0;
  }
}

// ---------------- K1: q_repr = e_emb @ W_q^T via MFMA (B x 256, K=256) -----
__global__ __launch_bounds__(256) void qrepr_mfma_kernel(
    const float* __restrict__ e_emb, const short* __restrict__ Wqb,
    float* __restrict__ q_out) {
  const int t = threadIdx.x;
  const int lane = t & 63;
  const int w = t >> 6;
  const int r0 = blockIdx.x * 16;
  const int am = lane & 15;
  const int ak = (lane >> 4) * 8;
  f32x4 acc[4] = {};
  const short* wbase = Wqb + (size_t)(w * 4) * 8 * 512;
#pragma unroll
  for (int ks = 0; ks < 8; ++ks) {
    const float4* s4 =
        (const float4*)(e_emb + (size_t)(r0 + am) * E_SZ + ks * 32 + ak);
    float4 a0 = s4[0], a1 = s4[1];
    bf16x8 av;
    av[0] = f2bf(a0.x); av[1] = f2bf(a0.y); av[2] = f2bf(a0.z); av[3] = f2bf(a0.w);
    av[4] = f2bf(a1.x); av[5] = f2bf(a1.y); av[6] = f2bf(a1.z); av[7] = f2bf(a1.w);
#pragma unroll
    for (int s = 0; s < 4; ++s) {
      bf16x8 bv = *(const bf16x8*)(wbase + (((size_t)(s * 8 + ks)) * 64 + lane) * 8);
      acc[s] = __builtin_amdgcn_mfma_f32_16x16x32_bf16(av, bv, acc[s], 0, 0, 0);
    }
  }
#pragma unroll
  for (int s = 0; s < 4; ++s) {
    const int col = w * 64 + s * 16 + am;
#pragma unroll
    for (int reg = 0; reg < 4; ++reg) {
      const int row = (lane >> 4) * 4 + reg;
      q_out[(size_t)(r0 + row) * E_SZ + col] = acc[s][reg];
    }
  }
}

// ---------------- K2 v3: fused messages GEMM + decay + softmax + PNA -------
// 256 blocks x 4 serial batches; 512 threads = 8 waves.
// wave w: rh = w>>1 (16-row group of 64-row tile), cg = w&1 (128-col group).
// W_rel staged once in LDS; A-fragments global->regs; attention accumulator
// in registers => 2 barriers per tile, 4 tiles per batch.
#define AGG_LDS_BYTES 147456

__global__ __launch_bounds__(512, 1) void agg_kernel(
    const float* __restrict__ rel, const float* __restrict__ ent,
    const int* __restrict__ htime, const int* __restrict__ qtime,
    const void* __restrict__ mask, const int* __restrict__ mflag,
    const short* __restrict__ wrelb, const float* __restrict__ qws,
    const float* __restrict__ e_emb, const float* __restrict__ log_gamma,
    short* __restrict__ comb) {
  extern __shared__ char smem[];
  short* Wsw = (short*)smem;                      //      0 .. 131072
  float* q_s = (float*)(smem + 131072);           // 256 f
  float* s_part = (float*)(smem + 132096);        // [64][2]
  float* decay_s = (float*)(smem + 132608);       // [256]
  float* maskf_s = (float*)(smem + 133632);       // [256]
  float* p_s = (float*)(smem + 134656);           // [64]
  float* scal = (float*)(smem + 134912);          // {m, l, alpha, nv}
  float* mean_part = (float*)(smem + 134928);     // [4][256]
  float* max_part = (float*)(smem + 139024);      // [4][256]
  float* attn_part = (float*)(smem + 143120);     // [4][256]

  const int t = threadIdx.x;
  const int lane = t & 63;
  const int w = t >> 6;
  const int rh = w >> 1;           // 0..3
  const int cg = w & 1;            // 0..1
  const int q4 = lane >> 4;
  const int cl = lane & 15;
  const int am = lane & 15;
  const float gamma = expf(log_gamma[0]);
  const int is_b8 = *mflag;

  // stage W_rel fragments once (128 KB, coalesced vector copy)
  for (int i = t; i < 8192; i += 512)
    ((bf16x8*)Wsw)[i] = ((const bf16x8*)wrelb)[i];

  for (int bi = 0; bi < 4; ++bi) {
    const int b = blockIdx.x + 256 * bi;
    const float qtf = (float)qtime[b];
    if (t < 256) {
      q_s[t] = qws[(size_t)b * E_SZ + t];
      float mf = 0.f, dc = 0.f;
      if (t < H_SZ) {
        mf = mask_at(mask, (size_t)b * H_SZ + t, is_b8);
        float td = fmaxf(qtf - (float)htime[(size_t)b * H_SZ + t], 0.f);
        dc = expf(-gamma * td);
      }
      maskf_s[t] = mf;
      decay_s[t] = dc;
    }
    if (t == 0) { scal[0] = NEG_HUGE; scal[1] = 0.f; scal[2] = 0.f; scal[3] = 0.f; }
    float attn_r[8] = {0.f, 0.f, 0.f, 0.f, 0.f, 0.f, 0.f, 0.f};
    float mean4[8] = {0.f, 0.f, 0.f, 0.f, 0.f, 0.f, 0.f, 0.f};
    float max4[8] = {NEG_HUGE, NEG_HUGE, NEG_HUGE, NEG_HUGE,
                     NEG_HUGE, NEG_HUGE, NEG_HUGE, NEG_HUGE};
    __syncthreads();  // covers W staging (first iter), q_s/mask/decay/scal
    if (t < H_SZ) atomicAdd(&scal[3], maskf_s[t]);

    for (int tile = 0; tile < 4; ++tile) {
      const int h0 = tile * 64;
      // ---- A fragments: global -> regs (row h0+rh*16+am, 256 k) ----
      bf16x8 af[8];
      const int hA = h0 + rh * 16 + am;
      if (hA < H_SZ) {
        const float4* src = (const float4*)(rel + ((size_t)b * H_SZ + hA) * R_SZ);
#pragma unroll
        for (int ks = 0; ks < 8; ++ks) {
          float4 a0 = src[ks * 8 + q4 * 2];
          float4 a1 = src[ks * 8 + q4 * 2 + 1];
          bf16x8 v;
          v[0] = f2bf(a0.x); v[1] = f2bf(a0.y); v[2] = f2bf(a0.z); v[3] = f2bf(a0.w);
          v[4] = f2bf(a1.x); v[5] = f2bf(a1.y); v[6] = f2bf(a1.z); v[7] = f2bf(a1.w);
          af[ks] = v;
        }
      } else {
#pragma unroll
        for (int ks = 0; ks < 8; ++ks) af[ks] = bf16x8{};
      }

      // ---- MFMA: rp[16x128 per wave] ----
      f32x4 acc[8] = {};
#pragma unroll
      for (int ks = 0; ks < 8; ++ks) {
#pragma unroll
        for (int sub = 0; sub < 8; ++sub) {
          bf16x8 bv = *(bf16x8*)(Wsw + ((((cg * 8 + sub) * 8 + ks) * 64 + lane) << 3));
          acc[sub] = __builtin_amdgcn_mfma_f32_16x16x32_bf16(af[ks], bv, acc[sub], 0, 0, 0);
        }
      }

      // ---- epilogue: msg = rp*ent; mean/max; score partials ----
      float msgv[32];  // [reg][sub]
      float sc[4];
#pragma unroll
      for (int reg = 0; reg < 4; ++reg) {
        const int row = rh * 16 + q4 * 4 + reg;
        const int h = h0 + row;
        const float mf = maskf_s[h & 255];
        const bool realrow = (h < H_SZ);
        float srow = 0.f;
#pragma unroll
        for (int sub = 0; sub < 8; ++sub) {
          const int e = cg * 128 + sub * 16 + cl;
          float entv = realrow ? ent[((size_t)b * H_SZ + h) * E_SZ + e] : 0.f;
          float m = acc[sub][reg] * entv;
          msgv[reg * 8 + sub] = m;
          mean4[sub] += mf * m;
          float cand = realrow ? (mf != 0.f ? m : 0.f) : NEG_HUGE;
          max4[sub] = fmaxf(max4[sub], cand);
          srow += q_s[e] * m;
        }
        sc[reg] = srow;
      }
#pragma unroll
      for (int m = 1; m <= 8; m <<= 1)
#pragma unroll
        for (int reg = 0; reg < 4; ++reg) sc[reg] += __shfl_xor(sc[reg], m, 64);
      if (cl == 0)
#pragma unroll
        for (int reg = 0; reg < 4; ++reg)
          s_part[(rh * 16 + q4 * 4 + reg) * 2 + cg] = sc[reg];
      __syncthreads();  // B1

      // ---- online softmax (wave 0; 64 lanes = 64 rows) ----
      if (w == 0) {
        const int row = lane;
        const int h = h0 + row;
        float srow = s_part[row * 2] + s_part[row * 2 + 1];
        float s;
        if (h >= H_SZ) s = NEG_HUGE;
        else if (maskf_s[h] == 0.f) s = -1e9f;
        else s = decay_s[h] * srow * 0.0625f;  // / sqrt(256)
        float mt = s;
#pragma unroll
        for (int m = 1; m <= 32; m <<= 1) mt = fmaxf(mt, __shfl_xor(mt, m, 64));
        const float m_old = scal[0];
        const float m_new = fmaxf(m_old, mt);
        const float alpha = expf(m_old - m_new);
        const float p = expf(s - m_new);
        float lt = p;
#pragma unroll
        for (int m = 1; m <= 32; m <<= 1) lt += __shfl_xor(lt, m, 64);
        if (lane == 0) {
          scal[0] = m_new;
          scal[1] = scal[1] * alpha + lt;
          scal[2] = alpha;
        }
        p_s[row] = p;
      }
      __syncthreads();  // B2

      // ---- register attention accumulation ----
      const float alpha = scal[2];
#pragma unroll
      for (int sub = 0; sub < 8; ++sub) {
        float v = attn_r[sub] * alpha;
#pragma unroll
        for (int reg = 0; reg < 4; ++reg)
          v += p_s[rh * 16 + q4 * 4 + reg] * msgv[reg * 8 + sub];
        attn_r[sub] = v;
      }
    }  // tiles

    // ---- finale: reduce over q4 lanes, then rh waves ----
#pragma unroll
    for (int sub = 0; sub < 8; ++sub) {
      mean4[sub] += __shfl_xor(mean4[sub], 16, 64);
      mean4[sub] += __shfl_xor(mean4[sub], 32, 64);
      max4[sub] = fmaxf(max4[sub], __shfl_xor(max4[sub], 16, 64));
      max4[sub] = fmaxf(max4[sub], __shfl_xor(max4[sub], 32, 64));
      attn_r[sub] += __shfl_xor(attn_r[sub], 16, 64);
      attn_r[sub] += __shfl_xor(attn_r[sub], 32, 64);
    }
    if (q4 == 0) {
#pragma unroll
      for (int sub = 0; sub < 8; ++sub) {
        const int e = cg * 128 + sub * 16 + cl;
        mean_part[rh * 256 + e] = mean4[sub];
        max_part[rh * 256 + e] = max4[sub];
        attn_part[rh * 256 + e] = attn_r[sub];
      }
    }
    __syncthreads();
    if (t < 256) {
      float mv = mean_part[t] + mean_part[256 + t] + mean_part[512 + t] +
                 mean_part[768 + t];
      float xv = fmaxf(fmaxf(max_part[t], max_part[256 + t]),
                       fmaxf(max_part[512 + t], max_part[768 + t]));
      float av = attn_part[t] + attn_part[256 + t] + attn_part[512 + t] +
                 attn_part[768 + t];
      const float nv = fmaxf(scal[3], 1.f);
      const float l = scal[1];
      short* dst = comb + (size_t)b * 1024;
      dst[t] = f2bf(mv / nv);
      dst[256 + t] = f2bf(xv);
      dst[512 + t] = f2bf(av / l);
      dst[768 + t] = f2bf(e_emb[(size_t)b * E_SZ + t]);
    }
    __syncthreads();  // protect LDS reuse by next batch
  }  // bi
}

// ---------------- K3: fused MLP chain (comb -> h1 -> dyn -> ctx) -----------
__global__ __launch_bounds__(256) void mlp_fused_kernel(
    const short* __restrict__ comb, const short* __restrict__ w1b,
    const float* __restrict__ b1, const float* __restrict__ ln1g,
    const float* __restrict__ ln1b, const short* __restrict__ w2b,
    const float* __restrict__ b2, const float* __restrict__ ln2g,
    const float* __restrict__ ln2b, const short* __restrict__ wcb,
    const float* __restrict__ bc, const float* __restrict__ lncg,
    const float* __restrict__ lncb, float* __restrict__ dyn,
    float* __restrict__ ctx) {
  __shared__ float pre[16][516];
  __shared__ float red[16][2];
  __shared__ short x1[16][520];  // h1 bf16 (K=512 for stage 2)
  __shared__ short x2[16][264];  // dyn bf16 (K=256 for stage 3)
  const int t = threadIdx.x;
  const int lane = t & 63;
  const int w = t >> 6;
  const int r0 = blockIdx.x * 16;
  const int am = lane & 15;
  const int ak = (lane >> 4) * 8;
  const int cr = lane >> 4;

  // ======== stage 1: comb[16][1024] @ W1^T -> pre[16][512] ========
  {
    f32x4 acc[8] = {};
    const short* wbase = w1b + (size_t)(w * 8) * 32 * 512;
    for (int ks = 0; ks < 32; ++ks) {
      bf16x8 av = *(const bf16x8*)(comb + (size_t)(r0 + am) * 1024 + ks * 32 + ak);
#pragma unroll
      for (int s = 0; s < 8; ++s) {
        bf16x8 bv = *(const bf16x8*)(wbase + ((size_t)(s * 32 + ks) * 64 + lane) * 8);
        acc[s] = __builtin_amdgcn_mfma_f32_16x16x32_bf16(av, bv, acc[s], 0, 0, 0);
      }
    }
#pragma unroll
    for (int s = 0; s < 8; ++s) {
      const int col = w * 128 + s * 16 + am;
      const float bv = b1[col];
#pragma unroll
      for (int reg = 0; reg < 4; ++reg) pre[cr * 4 + reg][col] = acc[s][reg] + bv;
    }
  }
  __syncthreads();
  {  // LN1 stats
    const int row = t >> 4, ch = t & 15;
    float s1 = 0.f, s2 = 0.f;
    for (int c = ch; c < 512; c += 16) { float v = pre[row][c]; s1 += v; s2 += v * v; }
#pragma unroll
    for (int m = 1; m <= 8; m <<= 1) { s1 += __shfl_xor(s1, m, 64); s2 += __shfl_xor(s2, m, 64); }
    if (ch == 0) { red[row][0] = s1 / 512.f; red[row][1] = s2 / 512.f; }
  }
  __syncthreads();
  for (int i = t; i < 16 * 512; i += 256) {  // LN1 + GELU -> x1 (bf16)
    const int row = i >> 9, c = i & 511;
    const float mu = red[row][0];
    const float var = fmaxf(red[row][1] - mu * mu, 0.f);
    float x = (pre[row][c] - mu) * rsqrtf(var + LN_EPS) * ln1g[c] + ln1b[c];
    x = 0.5f * x * (1.f + erff(x * 0.70710678118654752f));
    x1[row][c] = f2bf(x);
  }
  __syncthreads();

  // ======== stage 2: x1[16][512] @ W2^T -> pre[16][256] ========
  {
    f32x4 acc[4] = {};
    const short* wbase = w2b + (size_t)(w * 4) * 16 * 512;
    for (int ks = 0; ks < 16; ++ks) {
      bf16x8 av = *(const bf16x8*)(&x1[am][ks * 32 + ak]);
#pragma unroll
      for (int s = 0; s < 4; ++s) {
        bf16x8 bv = *(const bf16x8*)(wbase + ((size_t)(s * 16 + ks) * 64 + lane) * 8);
        acc[s] = __builtin_amdgcn_mfma_f32_16x16x32_bf16(av, bv, acc[s], 0, 0, 0);
      }
    }
    __syncthreads();
#pragma unroll
    for (int s = 0; s < 4; ++s) {
      const int col = w * 64 + s * 16 + am;
      const float bv = b2[col];
#pragma unroll
      for (int reg = 0; reg < 4; ++reg) pre[cr * 4 + reg][col] = acc[s][reg] + bv;
    }
  }
  __syncthreads();
  {  // LN2 stats (N=256)
    const int row = t >> 4, ch = t & 15;
    float s1 = 0.f, s2 = 0.f;
    for (int c = ch; c < 256; c += 16) { float v = pre[row][c]; s1 += v; s2 += v * v; }
#pragma unroll
    for (int m = 1; m <= 8; m <<= 1) { s1 += __shfl_xor(s1, m, 64); s2 += __shfl_xor(s2, m, 64); }
    if (ch == 0) { red[row][0] = s1 / 256.f; red[row][1] = s2 / 256.f; }
  }
  __syncthreads();
  for (int i = t; i < 16 * 256; i += 256) {  // LN2 -> dyn (fp32) + x2 (bf16)
    const int row = i >> 8, c = i & 255;
    const float mu = red[row][0];
    const float var = fmaxf(red[row][1] - mu * mu, 0.f);
    float x = (pre[row][c] - mu) * rsqrtf(var + LN_EPS) * ln2g[c] + ln2b[c];
    dyn[(size_t)(r0 + row) * 256 + c] = x;
    x2[row][c] = f2bf(x);
  }
  __syncthreads();

  // ======== stage 3: x2[16][256] @ Wc^T -> pre[16][512] ========
  {
    f32x4 acc[8] = {};
    const short* wbase = wcb + (size_t)(w * 8) * 8 * 512;
    for (int ks = 0; ks < 8; ++ks) {
      bf16x8 av = *(const bf16x8*)(&x2[am][ks * 32 + ak]);
#pragma unroll
      for (int s = 0; s < 8; ++s) {
        bf16x8 bv = *(const bf16x8*)(wbase + ((size_t)(s * 8 + ks) * 64 + lane) * 8);
        acc[s] = __builtin_amdgcn_mfma_f32_16x16x32_bf16(av, bv, acc[s], 0, 0, 0);
      }
    }
    __syncthreads();
#pragma unroll
    for (int s = 0; s < 8; ++s) {
      const int col = w * 128 + s * 16 + am;
      const float bv = bc[col];
#pragma unroll
      for (int reg = 0; reg < 4; ++reg) pre[cr * 4 + reg][col] = acc[s][reg] + bv;
    }
  }
  __syncthreads();
  {  // LNc stats
    const int row = t >> 4, ch = t & 15;
    float s1 = 0.f, s2 = 0.f;
    for (int c = ch; c < 512; c += 16) { float v = pre[row][c]; s1 += v; s2 += v * v; }
#pragma unroll
    for (int m = 1; m <= 8; m <<= 1) { s1 += __shfl_xor(s1, m, 64); s2 += __shfl_xor(s2, m, 64); }
    if (ch == 0) { red[row][0] = s1 / 512.f; red[row][1] = s2 / 512.f; }
  }
  __syncthreads();
  for (int i = t; i < 16 * 512; i += 256) {  // LNc + GELU -> ctx (fp32)
    const int row = i >> 9, c = i & 511;
    const float mu = red[row][0];
    const float var = fmaxf(red[row][1] - mu * mu, 0.f);
    float x = (pre[row][c] - mu) * rsqrtf(var + LN_EPS) * lncg[c] + lncb[c];
    x = 0.5f * x * (1.f + erff(x * 0.70710678118654752f));
    ctx[(size_t)(r0 + row) * 512 + c] = x;
  }
}

extern "C" void kernel_launch(void* const* d_in, const int* in_sizes, int n_in,
                              void* d_out, int out_size, void* d_ws,
                              size_t ws_size, hipStream_t stream) {
  const float* e_emb = (const float*)d_in[0];
  const float* ent = (const float*)d_in[1];
  const float* rel = (const float*)d_in[2];
  const int* ht = (const int*)d_in[3];
  const int* qt = (const int*)d_in[4];
  const void* mask = d_in[5];
  const float* Wrel = (const float*)d_in[6];
  const float* Wq = (const float*)d_in[7];
  const float* lg = (const float*)d_in[8];
  const float* W1 = (const float*)d_in[9];
  const float* b1 = (const float*)d_in[10];
  const float* ln1g = (const float*)d_in[11];
  const float* ln1b = (const float*)d_in[12];
  const float* W2 = (const float*)d_in[13];
  const float* b2 = (const float*)d_in[14];
  const float* ln2g = (const float*)d_in[15];
  const float* ln2b = (const float*)d_in[16];
  const float* Wc = (const float*)d_in[17];
  const float* bc = (const float*)d_in[18];
  const float* lncg = (const float*)d_in[19];
  const float* lncb = (const float*)d_in[20];

  char* wsb = (char*)d_ws;
  int* mflag = (int*)wsb;
  short* w1b = (short*)(wsb + 4096);
  short* w2b = (short*)(wsb + 4096 + (1024u << 10));
  short* wcb = (short*)(wsb + 4096 + (1280u << 10));
  short* wqb = (short*)(wsb + 4096 + (1536u << 10));
  short* wrelb = (short*)(wsb + 4096 + (1664u << 10));
  float* q_ws = (float*)(wsb + 4096 + (1792u << 10));
  short* combb = (short*)(wsb + 4096 + (2816u << 10));
  float* dyn = (float*)d_out;                          // B x 256
  float* ctx = (float*)d_out + (size_t)B_SZ * E_SZ;    // B x 512

  (void)ws_size;
  (void)hipFuncSetAttribute((const void*)agg_kernel,
                            hipFuncAttributeMaxDynamicSharedMemorySize,
                            AGG_LDS_BYTES);

  wconv_all_kernel<<<449, 256, 0, stream>>>(
      W1, W2, Wc, Wq, Wrel, (const unsigned char*)mask,
      w1b, w2b, wcb, wqb, wrelb, mflag);
  qrepr_mfma_kernel<<<64, 256, 0, stream>>>(e_emb, wqb, q_ws);
  agg_kernel<<<256, 512, AGG_LDS_BYTES, stream>>>(rel, ent, ht, qt, mask, mflag,
                                                  wrelb, q_ws, e_emb, lg, combb);
  mlp_fused_kernel<<<64, 256, 0, stream>>>(combb, w1b, b1, ln1g, ln1b,
                                           w2b, b2, ln2g, ln2b,
                                           wcb, bc, lncg, lncb, dyn, ctx);
}